// Round 2
// baseline (1430.825 us; speedup 1.0000x reference)
//
#include <hip/hip_runtime.h>
#include <math.h>

#define H 1536
#define E 512
#define T 48
#define S 32
#define V 128
#define NB 256
#define BT 512      // 8 waves
#define JPB 6       // h indices per block
#define ROWS 24     // 4*JPB gate rows per block (per matrix)
#define RPW 3       // rows per wave per matrix
#define CHK 24      // floats per lane chunk (1536/64)
// dynamic LDS: whh2 (64 lanes * 145 float4) + one shared h-gather buffer
#define WHH2_B   (64 * 145 * 16)          // 148480
#define HBUF_B   (64 * 7 * 16)            // 7168
#define DYN_LDS  (WHH2_B + HBUF_B)        // 155648

typedef unsigned long long u64;

// ws layout (4-byte words):
//   [0, 8192)          reserved (zeroed, legacy)
//   [8192, 14336)      h2t   : u64[2][H]     tagged h2 fragments
//   [16384, 212992)    candt : u64[2][S*H]   tagged h1 candidates
//   [212992, 245760)   logitt: u64[2][S*NB]  tagged logit partials
//   [245760, 1032192)  xw1g  : float[NB][V*ROWS] block-private (plain)
#define H2_U64    4096
#define CAND_U64  8192
#define LOG_U64   106496
#define ZERO_W    245760
#define XW1_W     245760

__device__ __forceinline__ float sigf(float x) { return 1.0f / (1.0f + expf(-x)); }
__device__ __forceinline__ float wred(float acc) {
#pragma unroll
    for (int off = 32; off; off >>= 1) acc += __shfl_down(acc, off);
    return acc;
}

#define GLD64(p)    __hip_atomic_load((p), __ATOMIC_RELAXED, __HIP_MEMORY_SCOPE_AGENT)
#define GST64(p, v) __hip_atomic_store((p), (v), __ATOMIC_RELAXED, __HIP_MEMORY_SCOPE_AGENT)

__device__ __forceinline__ u64 pk(float v, unsigned g) {
    return ((u64)g << 32) | (u64)__float_as_uint(v);
}
__device__ __forceinline__ float    pvf(u64 x) { return __uint_as_float((unsigned)x); }
__device__ __forceinline__ unsigned ptg(u64 x) { return (unsigned)(x >> 32); }

__global__ void init_kernel(unsigned* u) {
    // zero all tagged regions (tags must restart <1 each dispatch)
    for (int i = blockIdx.x * blockDim.x + threadIdx.x; i < ZERO_W;
         i += gridDim.x * blockDim.x)
        u[i] = 0u;
}

// Barrier-free data-flow loop. Every published float carries its generation
// in the same 8-byte atomic word; consumers poll the data itself (arrival
// and payload in ONE coherence hop). Safety of parity reuse: entering round
// k requires observing ALL 256 blocks' round-(k-1) logit-partial tags; a
// block's publish follows its round-(k-1) reads (syncthreads drains vmcnt),
// so all reads of the parity we will overwrite at end of round k are done.
__global__ __launch_bounds__(BT, 1) void nas_persist(
    const int* __restrict__ input_id, const float* __restrict__ emb,
    const float* __restrict__ Wih1, const float* __restrict__ Whh1,
    const float* __restrict__ bih1, const float* __restrict__ bhh1,
    const float* __restrict__ Wih2, const float* __restrict__ Whh2,
    const float* __restrict__ bih2, const float* __restrict__ bhh2,
    const float* __restrict__ Wout, const float* __restrict__ bout,
    float* __restrict__ out, float* __restrict__ ws)
{
    const int b = blockIdx.x, tid = threadIdx.x;
    const int wave = tid >> 6, lane = tid & 63;

    u64* h2t    = (u64*)ws + H2_U64;      // [parity*H + i]
    u64* candt  = (u64*)ws + CAND_U64;    // [parity*S*H + p*H + i]
    u64* logitt = (u64*)ws + LOG_U64;     // [parity*S*NB + s*NB + b]
    float* xw1g = ws + XW1_W + (size_t)b * (V * ROWS);

    extern __shared__ char dyn_lds[];
    float4* whh2s = (float4*)dyn_lds;                 // [lane*145 + row*6 + j]
    float*  hbuf  = (float*)(dyn_lds + WHH2_B);       // chunked, stride 28

    __shared__ float gacc1[ROWS], g2f[ROWS], bsum2[ROWS], zlog[S], h2f[JPB];
    __shared__ float c1s[JPB], c2s[JPB], c1cand[S * JPB];
    __shared__ int   xid_s, pred_s;

    // ---------------- prologue ----------------
    if (tid < JPB) {
        c2s[tid] = 0.f;
        GST64(h2t + b * JPB + tid, pk(0.f, 1u));      // h2(-1)=0, parity 0, tag 1
    }
    if (tid < ROWS) {
        int r = (tid / JPB) * H + b * JPB + (tid % JPB);
        bsum2[tid] = bih2[r] + bhh2[r];
    }
    if (tid == 0) xid_s = *input_id;

    // ---- xw1 table -> global ws (uses whh2s region as emb staging) ----
    {
        const int k0 = wave * RPW;
        float4 wiA[RPW], wiB[RPW];
        float  bs[RPW];
#pragma unroll
        for (int i = 0; i < RPW; ++i) {
            int k = k0 + i;
            int r = (k / JPB) * H + b * JPB + (k % JPB);
            const float4* w = (const float4*)(Wih1 + (size_t)r * E);
            wiA[i] = w[lane]; wiB[i] = w[lane + 64];
            bs[i]  = bih1[r] + bhh1[r];
        }
        float4* stage = (float4*)dyn_lds;             // 2048 f4 = 32 KB
        for (int ch = 0; ch < 8; ++ch) {
            const float4* src = (const float4*)(emb + (size_t)ch * 16 * E);
            for (int m = tid; m < 2048; m += BT) stage[m] = src[m];
            __syncthreads();
            for (int vv = 0; vv < 16; ++vv) {
                float4 ea = stage[vv * 128 + lane];
                float4 eb = stage[vv * 128 + 64 + lane];
#pragma unroll
                for (int i = 0; i < RPW; ++i) {
                    float a = wiA[i].x * ea.x + wiA[i].y * ea.y + wiA[i].z * ea.z + wiA[i].w * ea.w
                            + wiB[i].x * eb.x + wiB[i].y * eb.y + wiB[i].z * eb.z + wiB[i].w * eb.w;
                    a = wred(a);
                    if (lane == 0) xw1g[(ch * 16 + vv) * ROWS + (k0 + i)] = a + bs[i];
                }
            }
            __syncthreads();
        }
    }

    // ---- Whh2 -> LDS (lane-chunked, odd-f4 stride 145) ----
    for (int k = 0; k < ROWS; ++k) {
        int r = (k / JPB) * H + b * JPB + (k % JPB);
        const float4* src = (const float4*)(Whh2 + (size_t)r * H);
        if (tid < 384) {
            int l = tid / 6, j = tid % 6;
            whh2s[l * 145 + k * 6 + j] = src[tid];
        }
    }
    __syncthreads();

    // ---- Whh1 + Wih2 rows -> registers (fully resident: launch_bounds(,1)) ----
    float w1[RPW][CHK], w2[RPW][CHK];
#pragma unroll
    for (int i = 0; i < RPW; ++i) {
        int k = wave * RPW + i;
        int r = (k / JPB) * H + b * JPB + (k % JPB);
        const float4* p1 = (const float4*)(Whh1 + (size_t)r * H) + lane * 6;
        const float4* p2 = (const float4*)(Wih2 + (size_t)r * H) + lane * 6;
#pragma unroll
        for (int j = 0; j < 6; ++j) {
            float4 v1 = p1[j], v2 = p2[j];
            w1[i][4 * j + 0] = v1.x; w1[i][4 * j + 1] = v1.y;
            w1[i][4 * j + 2] = v1.z; w1[i][4 * j + 3] = v1.w;
            w2[i][4 * j + 0] = v2.x; w2[i][4 * j + 1] = v2.y;
            w2[i][4 * j + 2] = v2.z; w2[i][4 * j + 3] = v2.w;
        }
    }
    __syncthreads();

    // ---- h1(0) from xid(0)=input_id; publish candidate slot 0, parity 0 ----
    if (tid < JPB) {
        const float* xr = xw1g + (size_t)xid_s * ROWS;
        float gi = xr[tid], gg = xr[2 * JPB + tid], go = xr[3 * JPB + tid];
        float cn = sigf(gi) * tanhf(gg);
        c1s[tid] = cn;
        GST64(candt + b * JPB + tid, pk(sigf(go) * tanhf(cn), 1u));
    }
    // no barrier: consumers poll tags

    // precomputed hbuf scatter maps (stride-28 chunked layout)
    const int m0 = (tid / CHK) * 28 + (tid % CHK);
    const int m1 = ((tid + 512) / CHK) * 28 + ((tid + 512) % CHK);
    const int m2 = ((tid + 1024) / CHK) * 28 + ((tid + 1024) % CHK);

    // ---------------- main loop: zero barriers, tag-polled data flow ----------------
    for (int k = 0; k <= T; ++k) {
        const unsigned expg = (unsigned)(k + 1);

        // issue h2(k-1) tagged loads first (oldest in vmcnt FIFO)
        const u64* h2src = h2t + (size_t)(k & 1) * H;
        u64 hv0 = 0, hv1 = 0, hv2 = 0;
        if (k < T) {
            hv0 = GLD64(h2src + tid);
            hv1 = GLD64(h2src + tid + 512);
            hv2 = GLD64(h2src + tid + 1024);
        }

        // logits(k-1): poll tagged partials, fixed-order reduce (bitwise-stable)
        if (k > 0) {
            const u64* lp = logitt + (size_t)(k & 1) * (S * NB)
                            + (tid >> 4) * NB + (tid & 15) * 16;
            u64 pvv[16];
            for (;;) {
                bool ok = true;
#pragma unroll
                for (int i = 0; i < 16; ++i) pvv[i] = GLD64(lp + i);
#pragma unroll
                for (int i = 0; i < 16; ++i) ok &= (ptg(pvv[i]) >= expg);
                if (ok) break;
                __builtin_amdgcn_s_sleep(1);
            }
            float acc = 0.f;
#pragma unroll
            for (int i = 0; i < 16; ++i) acc += pvf(pvv[i]);
#pragma unroll
            for (int off = 8; off; off >>= 1) acc += __shfl_down(acc, off, 16);
            if ((tid & 15) == 0)
                zlog[tid >> 4] = acc + bout[(size_t)(k - 1) * S + (tid >> 4)];
        }

        // Wout slice for THIS round's tail partials: issue AFTER the
        // pred-critical polls (vmcnt FIFO: first drained at the h1 wait,
        // ~0.5us of cover by then)
        float wcol[JPB];
        if (k < T && wave == 0 && lane < S) {
            const float* wp = Wout + ((size_t)k * S + lane) * H + b * JPB;
#pragma unroll
            for (int j = 0; j < JPB; ++j) wcol[j] = wp[j];
        }

        // h2 tag check (normally already satisfied) + scatter to LDS
        if (k < T) {
            for (;;) {
                bool ok = (ptg(hv0) >= expg) && (ptg(hv1) >= expg) && (ptg(hv2) >= expg);
                if (ok) break;
                __builtin_amdgcn_s_sleep(1);
                hv0 = GLD64(h2src + tid);
                hv1 = GLD64(h2src + tid + 512);
                hv2 = GLD64(h2src + tid + 1024);
            }
            hbuf[m0] = pvf(hv0); hbuf[m1] = pvf(hv1); hbuf[m2] = pvf(hv2);
        }
        __syncthreads();                       // zlog + hbuf visible

        if (k > 0) {
            if (wave == 0) {
                float z = (lane < S) ? zlog[lane] : -1e30f;
                float v = z; int idx = (lane < S) ? lane : 9999;
#pragma unroll
                for (int off = 32; off; off >>= 1) {
                    float ov = __shfl_xor(v, off); int oi = __shfl_xor(idx, off);
                    if (ov > v || (ov == v && oi < idx)) { v = ov; idx = oi; }
                }
                float e = (lane < S) ? expf(z - v) : 0.f;
#pragma unroll
                for (int off = 32; off; off >>= 1) e += __shfl_xor(e, off);
                if (lane == 0) pred_s = idx;
                if (b == 0 && lane < S) out[(size_t)(k - 1) * S + lane] = z - v - logf(e);
            }
            __syncthreads();
        }
        if (k == T) return;                    // out[T-1] written; done
        const int psel = (k > 0) ? pred_s : 0;
        if (k > 0 && tid < JPB) c1s[tid] = c1cand[psel * JPB + tid];

        // issue h1(k) tagged loads now; gaccH compute hides the hop
        const u64* h1src = candt + (size_t)(k & 1) * (S * H) + (size_t)psel * H;
        u64 tv0 = GLD64(h1src + tid);
        u64 tv1 = GLD64(h1src + tid + 512);
        u64 tv2 = GLD64(h1src + tid + 1024);

        float h2c[CHK];
        {
            const float4* hp = (const float4*)hbuf + lane * 7;
#pragma unroll
            for (int j = 0; j < 6; ++j) {
                float4 v = hp[j];
                h2c[4 * j + 0] = v.x; h2c[4 * j + 1] = v.y;
                h2c[4 * j + 2] = v.z; h2c[4 * j + 3] = v.w;
            }
        }
        float ahv[RPW];
#pragma unroll
        for (int i = 0; i < RPW; ++i) {
            int kk = wave * RPW + i;
            const float4* wp = whh2s + lane * 145 + kk * 6;
            float ah = 0.f;
#pragma unroll
            for (int j = 0; j < 6; ++j) {
                float4 v = wp[j];
                ah += v.x * h2c[4 * j + 0] + v.y * h2c[4 * j + 1]
                    + v.z * h2c[4 * j + 2] + v.w * h2c[4 * j + 3];
            }
            ahv[i] = wred(ah);                 // valid at lane 0
        }
        __syncthreads();                       // hbuf free for h1

        for (;;) {
            bool ok = (ptg(tv0) >= expg) && (ptg(tv1) >= expg) && (ptg(tv2) >= expg);
            if (ok) break;
            __builtin_amdgcn_s_sleep(1);
            tv0 = GLD64(h1src + tid);
            tv1 = GLD64(h1src + tid + 512);
            tv2 = GLD64(h1src + tid + 1024);
        }
        hbuf[m0] = pvf(tv0); hbuf[m1] = pvf(tv1); hbuf[m2] = pvf(tv2);
        __syncthreads();

        float h1c[CHK];
        {
            const float4* hp = (const float4*)hbuf + lane * 7;
#pragma unroll
            for (int j = 0; j < 6; ++j) {
                float4 v = hp[j];
                h1c[4 * j + 0] = v.x; h1c[4 * j + 1] = v.y;
                h1c[4 * j + 2] = v.z; h1c[4 * j + 3] = v.w;
            }
        }
        // D1: Whh1 @ h1(k), Wih2 @ h1(k) (register weights)
        float a1[RPW], a2[RPW];
#pragma unroll
        for (int i = 0; i < RPW; ++i) { a1[i] = 0.f; a2[i] = 0.f; }
#pragma unroll
        for (int kk = 0; kk < CHK; ++kk) {
            float h = h1c[kk];
#pragma unroll
            for (int i = 0; i < RPW; ++i) {
                a1[i] += w1[i][kk] * h;
                a2[i] += w2[i][kk] * h;
            }
        }
#pragma unroll
        for (int i = 0; i < RPW; ++i) {
            int kk = wave * RPW + i;
            float s1 = wred(a1[i]);
            float s2 = wred(a2[i]);
            if (lane == 0) {
                gacc1[kk] = s1;
                g2f[kk]   = s2 + ahv[i] + bsum2[kk];
            }
        }
        __syncthreads();

        const unsigned newg = (unsigned)(k + 2);
        // P2: h2(k) fragment -> publish tagged to parity (k+1)&1
        if (tid < JPB) {
            float gi = g2f[tid],           gf = g2f[JPB + tid];
            float gg = g2f[2 * JPB + tid], go = g2f[3 * JPB + tid];
            float cn = sigf(gf) * c2s[tid] + sigf(gi) * tanhf(gg);
            c2s[tid] = cn;
            float hn = sigf(go) * tanhf(cn);
            h2f[tid] = hn;
            GST64(h2t + (size_t)((k + 1) & 1) * H + b * JPB + tid, pk(hn, newg));
        }
        // candidates for h1(k+1): all 32 possible preds; publish tagged fragments
        if (tid < S * JPB) {
            int p = tid / JPB, j = tid % JPB;
            const float* xr = xw1g + (size_t)((k & 3) * S + p) * ROWS;
            float gi = gacc1[j]           + xr[j];
            float gf = gacc1[JPB + j]     + xr[JPB + j];
            float gg = gacc1[2 * JPB + j] + xr[2 * JPB + j];
            float go = gacc1[3 * JPB + j] + xr[3 * JPB + j];
            float cn = sigf(gf) * c1s[j] + sigf(gi) * tanhf(gg);
            c1cand[tid] = cn;
            GST64(candt + (size_t)((k + 1) & 1) * (S * H) + (size_t)p * H + b * JPB + j,
                  pk(sigf(go) * tanhf(cn), newg));
        }
        __syncthreads();                       // h2f visible to wave 0
        // producer-side partial logits(k): this block's 6-column contribution
        if (wave == 0 && lane < S) {
            float p = 0.f;
#pragma unroll
            for (int j = 0; j < JPB; ++j) p += wcol[j] * h2f[j];
            GST64(logitt + (size_t)((k + 1) & 1) * (S * NB) + lane * NB + b,
                  pk(p, newg));
        }
        // no barrier: next round's polls gate everything
    }
}

extern "C" void kernel_launch(void* const* d_in, const int* in_sizes, int n_in,
                              void* d_out, int out_size, void* d_ws, size_t ws_size,
                              hipStream_t stream) {
    const int*   input_id = (const int*)d_in[0];
    const float* emb  = (const float*)d_in[1];
    const float* Wih1 = (const float*)d_in[2];
    const float* Whh1 = (const float*)d_in[3];
    const float* bih1 = (const float*)d_in[4];
    const float* bhh1 = (const float*)d_in[5];
    const float* Wih2 = (const float*)d_in[6];
    const float* Whh2 = (const float*)d_in[7];
    const float* bih2 = (const float*)d_in[8];
    const float* bhh2 = (const float*)d_in[9];
    const float* Wout = (const float*)d_in[10];
    const float* bout = (const float*)d_in[11];
    float* out = (float*)d_out;
    float* ws  = (float*)d_ws;

    init_kernel<<<256, 256, 0, stream>>>((unsigned*)ws);

    void* args[] = { (void*)&input_id, (void*)&emb,
                     (void*)&Wih1, (void*)&Whh1, (void*)&bih1, (void*)&bhh1,
                     (void*)&Wih2, (void*)&Whh2, (void*)&bih2, (void*)&bhh2,
                     (void*)&Wout, (void*)&bout, (void*)&out, (void*)&ws };
    hipLaunchCooperativeKernel((void*)nas_persist, dim3(NB), dim3(BT), args,
                               DYN_LDS, stream);
}

// Round 3
// 1185.652 us; speedup vs baseline: 1.2068x; 1.2068x over previous
//
#include <hip/hip_runtime.h>
#include <math.h>

#define H 1536
#define E 512
#define T 48
#define S 32
#define V 128
#define NB 256
#define BT 512      // 8 waves
#define JPB 6       // h indices per block
#define ROWS 24     // 4*JPB gate rows per block (per matrix)
#define RPW 3       // rows per wave per matrix
#define CHK 24      // floats per lane chunk (1536/64)
// dynamic LDS: whh2 (64 lanes * 145 float4) + one shared h-gather buffer
#define WHH2_B   (64 * 145 * 16)          // 148480
#define HBUF_B   (64 * 7 * 16)            // 7168
#define DYN_LDS  (WHH2_B + HBUF_B)        // 155648

typedef unsigned long long u64;

// ws layout:
//   u64[0]                  predt   {pred, gen} broadcast word
//   u64[2048 .. 18432)      logitt  2 parities x S*NB tagged partials
//   word[36864 .. 39936)    h2g     2 parities x H plain f32
//   word[40960 .. 139264)   candp   2 parities x S*H plain f32
//   word[139264 .. 925696)  xw1g    NB x V*ROWS block-private plain
#define PRED_U64  0
#define LOG_U64   2048
#define H2_W      36864
#define CAND_W    40960
#define XW1_W     139264
#define ZERO_W    36864     // zero predt+logitt region [0, 36864) words

__device__ __forceinline__ float sigf(float x) { return 1.0f / (1.0f + expf(-x)); }
__device__ __forceinline__ float wred(float acc) {
#pragma unroll
    for (int off = 32; off; off >>= 1) acc += __shfl_down(acc, off);
    return acc;
}

#define GLD(p)      __hip_atomic_load((p), __ATOMIC_RELAXED, __HIP_MEMORY_SCOPE_AGENT)
#define GST(p, v)   __hip_atomic_store((p), (v), __ATOMIC_RELAXED, __HIP_MEMORY_SCOPE_AGENT)
#define GLD64(p)    __hip_atomic_load((p), __ATOMIC_RELAXED, __HIP_MEMORY_SCOPE_AGENT)
#define GST64(p, v) __hip_atomic_store((p), (v), __ATOMIC_RELAXED, __HIP_MEMORY_SCOPE_AGENT)

__device__ __forceinline__ u64 pkf(float v, unsigned g) {
    return ((u64)g << 32) | (u64)__float_as_uint(v);
}
__device__ __forceinline__ u64 pki(int v, unsigned g) {
    return ((u64)g << 32) | (u64)(unsigned)v;
}
__device__ __forceinline__ float    pvf(u64 x) { return __uint_as_float((unsigned)x); }
__device__ __forceinline__ unsigned ptg(u64 x) { return (unsigned)(x >> 32); }

__global__ void init_kernel(unsigned* u) {
    for (int i = blockIdx.x * blockDim.x + threadIdx.x; i < ZERO_W;
         i += gridDim.x * blockDim.x)
        u[i] = 0u;
}

// Centralized tagged dataflow:
//  - producers publish plain h2/cand fragments, then ONE tagged logit-partial
//    word per (s, block) [flag and payload fused].
//  - block 0 alone polls all partials (tag >= k+1), reduces from the polled
//    registers (no second data hop), argmaxes, writes out(k-1), and
//    broadcasts a single tagged {pred, gen} word.
//  - 255 blocks poll ONE u64 with one thread each (minimal coherent traffic),
//    then gather h2/h1 with plain f32 loads (freshness proven transitively
//    through the tag chain; same syncthreads-drains-before-tag discipline
//    as rounds 0-1).
__global__ __launch_bounds__(BT, 1) void nas_persist(
    const int* __restrict__ input_id, const float* __restrict__ emb,
    const float* __restrict__ Wih1, const float* __restrict__ Whh1,
    const float* __restrict__ bih1, const float* __restrict__ bhh1,
    const float* __restrict__ Wih2, const float* __restrict__ Whh2,
    const float* __restrict__ bih2, const float* __restrict__ bhh2,
    const float* __restrict__ Wout, const float* __restrict__ bout,
    float* __restrict__ out, float* __restrict__ ws)
{
    const int b = blockIdx.x, tid = threadIdx.x;
    const int wave = tid >> 6, lane = tid & 63;

    u64* predt  = (u64*)ws + PRED_U64;
    u64* logitt = (u64*)ws + LOG_U64;     // [parity*S*NB + s*NB + b]
    float* h2gp[2]  = { ws + H2_W,   ws + H2_W + H };
    float* candp[2] = { ws + CAND_W, ws + CAND_W + S * H };
    float* xw1g = ws + XW1_W + (size_t)b * (V * ROWS);

    extern __shared__ char dyn_lds[];
    float4* whh2s = (float4*)dyn_lds;                 // [lane*145 + row*6 + j]
    float*  hbuf  = (float*)(dyn_lds + WHH2_B);       // chunked, stride 28

    __shared__ float gacc1[ROWS], g2f[ROWS], bsum2[ROWS], zlog[S], h2f[JPB];
    __shared__ float c1s[JPB], c2s[JPB], c1cand[S * JPB];
    __shared__ int   xid_s, pred_s;

    // ---------------- prologue ----------------
    if (tid < JPB) { c2s[tid] = 0.f; GST(h2gp[0] + b * JPB + tid, 0.f); }
    if (tid < ROWS) {
        int r = (tid / JPB) * H + b * JPB + (tid % JPB);
        bsum2[tid] = bih2[r] + bhh2[r];
    }
    if (tid == 0) xid_s = *input_id;

    // ---- xw1 table -> global ws (uses whh2s region as emb staging) ----
    {
        const int k0 = wave * RPW;
        float4 wiA[RPW], wiB[RPW];
        float  bs[RPW];
#pragma unroll
        for (int i = 0; i < RPW; ++i) {
            int k = k0 + i;
            int r = (k / JPB) * H + b * JPB + (k % JPB);
            const float4* w = (const float4*)(Wih1 + (size_t)r * E);
            wiA[i] = w[lane]; wiB[i] = w[lane + 64];
            bs[i]  = bih1[r] + bhh1[r];
        }
        float4* stage = (float4*)dyn_lds;             // 2048 f4 = 32 KB
        for (int ch = 0; ch < 8; ++ch) {
            const float4* src = (const float4*)(emb + (size_t)ch * 16 * E);
            for (int m = tid; m < 2048; m += BT) stage[m] = src[m];
            __syncthreads();
            for (int vv = 0; vv < 16; ++vv) {
                float4 ea = stage[vv * 128 + lane];
                float4 eb = stage[vv * 128 + 64 + lane];
#pragma unroll
                for (int i = 0; i < RPW; ++i) {
                    float a = wiA[i].x * ea.x + wiA[i].y * ea.y + wiA[i].z * ea.z + wiA[i].w * ea.w
                            + wiB[i].x * eb.x + wiB[i].y * eb.y + wiB[i].z * eb.z + wiB[i].w * eb.w;
                    a = wred(a);
                    if (lane == 0) xw1g[(ch * 16 + vv) * ROWS + (k0 + i)] = a + bs[i];
                }
            }
            __syncthreads();
        }
    }

    // ---- Whh2 -> LDS (lane-chunked, odd-f4 stride 145) ----
    for (int k = 0; k < ROWS; ++k) {
        int r = (k / JPB) * H + b * JPB + (k % JPB);
        const float4* src = (const float4*)(Whh2 + (size_t)r * H);
        if (tid < 384) {
            int l = tid / 6, j = tid % 6;
            whh2s[l * 145 + k * 6 + j] = src[tid];
        }
    }
    __syncthreads();

    // ---- Whh1 + Wih2 rows -> registers ----
    float w1[RPW][CHK], w2[RPW][CHK];
#pragma unroll
    for (int i = 0; i < RPW; ++i) {
        int k = wave * RPW + i;
        int r = (k / JPB) * H + b * JPB + (k % JPB);
        const float4* p1 = (const float4*)(Whh1 + (size_t)r * H) + lane * 6;
        const float4* p2 = (const float4*)(Wih2 + (size_t)r * H) + lane * 6;
#pragma unroll
        for (int j = 0; j < 6; ++j) {
            float4 v1 = p1[j], v2 = p2[j];
            w1[i][4 * j + 0] = v1.x; w1[i][4 * j + 1] = v1.y;
            w1[i][4 * j + 2] = v1.z; w1[i][4 * j + 3] = v1.w;
            w2[i][4 * j + 0] = v2.x; w2[i][4 * j + 1] = v2.y;
            w2[i][4 * j + 2] = v2.z; w2[i][4 * j + 3] = v2.w;
        }
    }
    __syncthreads();

    // ---- h1(0) from xid(0)=input_id; publish candidate slot 0, parity 0 ----
    if (tid < JPB) {
        const float* xr = xw1g + (size_t)xid_s * ROWS;
        float gi = xr[tid], gg = xr[2 * JPB + tid], go = xr[3 * JPB + tid];
        float cn = sigf(gi) * tanhf(gg);
        c1s[tid] = cn;
        GST(candp[0] + b * JPB + tid, sigf(go) * tanhf(cn));   // slot 0, parity 0
    }
    __syncthreads();                        // drain publishes before done-tag
    if (tid == 0) GST64(logitt + b, pkf(0.f, 1u));   // prologue-done: parity0,s0

    // precomputed hbuf scatter maps (stride-28 chunked layout)
    const int m0 = (tid / CHK) * 28 + (tid % CHK);
    const int m1 = ((tid + 512) / CHK) * 28 + ((tid + 512) % CHK);
    const int m2 = ((tid + 1024) / CHK) * 28 + ((tid + 1024) % CHK);

    // ---------------- main loop ----------------
    for (int k = 0; k <= T; ++k) {
        // Wout slice prefetch (independent; drains under the pred gate)
        float wcol[JPB];
        if (k < T && wave == 0 && lane < S) {
            const float* wp = Wout + ((size_t)k * S + lane) * H + b * JPB;
#pragma unroll
            for (int j = 0; j < JPB; ++j) wcol[j] = wp[j];
        }

        // ---- pred gate ----
        if (b == 0) {
            if (k == 0) {
                if (tid < 64) {            // wave 0 polls prologue-done tags
                    const u64* lp = logitt + tid * 4;
                    for (;;) {
                        bool ok = (ptg(GLD64(lp + 0)) >= 1u) && (ptg(GLD64(lp + 1)) >= 1u)
                               && (ptg(GLD64(lp + 2)) >= 1u) && (ptg(GLD64(lp + 3)) >= 1u);
                        if (__all(ok)) break;
                        __builtin_amdgcn_s_sleep(1);
                    }
                }
                __syncthreads();
                if (tid == 0) { pred_s = 0; GST64(predt, pki(0, 1u)); }
                __syncthreads();
            } else {
                const unsigned eg = (unsigned)(k + 1);
                const u64* lp = logitt + (size_t)(k & 1) * (S * NB)
                                + (tid >> 4) * NB + (tid & 15) * 16;
                u64 pvv[16];
                for (;;) {
                    bool ok = true;
#pragma unroll
                    for (int i = 0; i < 16; ++i) pvv[i] = GLD64(lp + i);
#pragma unroll
                    for (int i = 0; i < 16; ++i) ok &= (ptg(pvv[i]) >= eg);
                    if (ok) break;
                    __builtin_amdgcn_s_sleep(1);
                }
                float acc = 0.f;
#pragma unroll
                for (int i = 0; i < 16; ++i) acc += pvf(pvv[i]);
#pragma unroll
                for (int off = 8; off; off >>= 1) acc += __shfl_down(acc, off, 16);
                if ((tid & 15) == 0)
                    zlog[tid >> 4] = acc + bout[(size_t)(k - 1) * S + (tid >> 4)];
                __syncthreads();
                if (wave == 0) {
                    float z = (lane < S) ? zlog[lane] : -1e30f;
                    float v = z; int idx = (lane < S) ? lane : 9999;
#pragma unroll
                    for (int off = 32; off; off >>= 1) {
                        float ov = __shfl_xor(v, off); int oi = __shfl_xor(idx, off);
                        if (ov > v || (ov == v && oi < idx)) { v = ov; idx = oi; }
                    }
                    float e = (lane < S) ? expf(z - v) : 0.f;
#pragma unroll
                    for (int off = 32; off; off >>= 1) e += __shfl_xor(e, off);
                    if (lane == 0) {
                        pred_s = idx;
                        GST64(predt, pki(idx, (unsigned)(k + 1)));
                    }
                    if (lane < S) out[(size_t)(k - 1) * S + lane] = z - v - logf(e);
                }
                __syncthreads();
            }
        } else {
            if (k == T) return;            // nothing left for non-head blocks
            if (tid == 0) {
                const unsigned eg = (unsigned)(k + 1);
                u64 v;
                for (;;) {
                    v = GLD64(predt);
                    if (ptg(v) >= eg) break;
                    __builtin_amdgcn_s_sleep(1);
                }
                pred_s = (int)(unsigned)v;
            }
            __syncthreads();
        }
        if (k == T) return;                // block 0: out[T-1] written above

        const int psel = pred_s;
        if (k > 0 && tid < JPB) c1s[tid] = c1cand[psel * JPB + tid];

        // ---- gathers: h2 (older in FIFO) then h1; hops overlap ----
        const float* h2src = h2gp[k & 1];
        float u0 = GLD(h2src + tid);
        float u1 = GLD(h2src + tid + 512);
        float u2 = GLD(h2src + tid + 1024);
        const float* h1src = candp[k & 1] + (size_t)psel * H;
        float t0 = GLD(h1src + tid);
        float t1 = GLD(h1src + tid + 512);
        float t2 = GLD(h1src + tid + 1024);

        hbuf[m0] = u0; hbuf[m1] = u1; hbuf[m2] = u2;   // h2 -> LDS
        __syncthreads();
        float h2c[CHK];
        {
            const float4* hp = (const float4*)hbuf + lane * 7;
#pragma unroll
            for (int j = 0; j < 6; ++j) {
                float4 v = hp[j];
                h2c[4 * j + 0] = v.x; h2c[4 * j + 1] = v.y;
                h2c[4 * j + 2] = v.z; h2c[4 * j + 3] = v.w;
            }
        }
        // Whh2 @ h2(k-1) (h1 gather still in flight underneath)
        float ahv[RPW];
#pragma unroll
        for (int i = 0; i < RPW; ++i) {
            int kk = wave * RPW + i;
            const float4* wp = whh2s + lane * 145 + kk * 6;
            float ah = 0.f;
#pragma unroll
            for (int j = 0; j < 6; ++j) {
                float4 v = wp[j];
                ah += v.x * h2c[4 * j + 0] + v.y * h2c[4 * j + 1]
                    + v.z * h2c[4 * j + 2] + v.w * h2c[4 * j + 3];
            }
            ahv[i] = wred(ah);             // valid at lane 0
        }
        __syncthreads();                   // hbuf free for h1
        hbuf[m0] = t0; hbuf[m1] = t1; hbuf[m2] = t2;
        __syncthreads();
        float h1c[CHK];
        {
            const float4* hp = (const float4*)hbuf + lane * 7;
#pragma unroll
            for (int j = 0; j < 6; ++j) {
                float4 v = hp[j];
                h1c[4 * j + 0] = v.x; h1c[4 * j + 1] = v.y;
                h1c[4 * j + 2] = v.z; h1c[4 * j + 3] = v.w;
            }
        }
        // D1: Whh1 @ h1(k), Wih2 @ h1(k) (register weights)
        float a1[RPW], a2[RPW];
#pragma unroll
        for (int i = 0; i < RPW; ++i) { a1[i] = 0.f; a2[i] = 0.f; }
#pragma unroll
        for (int kk = 0; kk < CHK; ++kk) {
            float h = h1c[kk];
#pragma unroll
            for (int i = 0; i < RPW; ++i) {
                a1[i] += w1[i][kk] * h;
                a2[i] += w2[i][kk] * h;
            }
        }
#pragma unroll
        for (int i = 0; i < RPW; ++i) {
            int kk = wave * RPW + i;
            float s1 = wred(a1[i]);
            float s2 = wred(a2[i]);
            if (lane == 0) {
                gacc1[kk] = s1;
                g2f[kk]   = s2 + ahv[i] + bsum2[kk];
            }
        }
        __syncthreads();

        // P2: h2(k) fragment -> publish plain to parity (k+1)&1
        if (tid < JPB) {
            float gi = g2f[tid],           gf = g2f[JPB + tid];
            float gg = g2f[2 * JPB + tid], go = g2f[3 * JPB + tid];
            float cn = sigf(gf) * c2s[tid] + sigf(gi) * tanhf(gg);
            c2s[tid] = cn;
            float hn = sigf(go) * tanhf(cn);
            h2f[tid] = hn;
            GST(h2gp[(k + 1) & 1] + b * JPB + tid, hn);
        }
        // candidates for h1(k+1): all 32 possible preds; publish fragments
        if (tid < S * JPB) {
            int p = tid / JPB, j = tid % JPB;
            const float* xr = xw1g + (size_t)((k & 3) * S + p) * ROWS;
            float gi = gacc1[j]           + xr[j];
            float gf = gacc1[JPB + j]     + xr[JPB + j];
            float gg = gacc1[2 * JPB + j] + xr[2 * JPB + j];
            float go = gacc1[3 * JPB + j] + xr[3 * JPB + j];
            float cn = sigf(gf) * c1s[j] + sigf(gi) * tanhf(gg);
            c1cand[tid] = cn;
            GST(candp[(k + 1) & 1] + (size_t)p * H + b * JPB + j,
                sigf(go) * tanhf(cn));
        }
        __syncthreads();                   // h2f visible + plain publishes drained
        // tagged partial logits(k): flag+payload fused, written LAST
        if (wave == 0 && lane < S) {
            float p = 0.f;
#pragma unroll
            for (int j = 0; j < JPB; ++j) p += wcol[j] * h2f[j];
            GST64(logitt + (size_t)((k + 1) & 1) * (S * NB) + lane * NB + b,
                  pkf(p, (unsigned)(k + 2)));
        }
    }
}

extern "C" void kernel_launch(void* const* d_in, const int* in_sizes, int n_in,
                              void* d_out, int out_size, void* d_ws, size_t ws_size,
                              hipStream_t stream) {
    const int*   input_id = (const int*)d_in[0];
    const float* emb  = (const float*)d_in[1];
    const float* Wih1 = (const float*)d_in[2];
    const float* Whh1 = (const float*)d_in[3];
    const float* bih1 = (const float*)d_in[4];
    const float* bhh1 = (const float*)d_in[5];
    const float* Wih2 = (const float*)d_in[6];
    const float* Whh2 = (const float*)d_in[7];
    const float* bih2 = (const float*)d_in[8];
    const float* bhh2 = (const float*)d_in[9];
    const float* Wout = (const float*)d_in[10];
    const float* bout = (const float*)d_in[11];
    float* out = (float*)d_out;
    float* ws  = (float*)d_ws;

    init_kernel<<<64, 256, 0, stream>>>((unsigned*)ws);

    void* args[] = { (void*)&input_id, (void*)&emb,
                     (void*)&Wih1, (void*)&Whh1, (void*)&bih1, (void*)&bhh1,
                     (void*)&Wih2, (void*)&Whh2, (void*)&bih2, (void*)&bhh2,
                     (void*)&Wout, (void*)&bout, (void*)&out, (void*)&ws };
    hipLaunchCooperativeKernel((void*)nas_persist, dim3(NB), dim3(BT), args,
                               DYN_LDS, stream);
}